// Round 1
// baseline (7355.562 us; speedup 1.0000x reference)
//
#include <hip/hip_runtime.h>
#include <hip/hip_bf16.h>
#include <math.h>

// ---------------------------------------------------------------------------
// InvertibleDenseBlockSVD: 3x [spectral-clip(W, 0.9) matmul + bias + act]
//
// Spectral clip without SVD:
//   H = W^T W ;  Z = sign(c^2 I - H)        (Newton-Schulz, quintic+cubic)
//   M' = (H(I-Z) + I + Z)/2                 (eigs: clipped lambdas and 1s)
//   G = (I+Z)/2 + (c/2)(I-Z) M'^{-1/2}      (coupled NS inverse sqrt)
//   kernel = W G                            ( == U min(S,c) V^T )
//
// Round 1: all fp32, simple tiled GEMM (correctness anchor, no MFMA yet).
// ---------------------------------------------------------------------------

static const long MUL = 1 << 20; // floats per 1024x1024 matrix

enum { EPI_NONE=0, EPI_POLY=1, EPI_Y0=2, EPI_TC=3, EPI_G=4, EPI_BACT=5, EPI_BIAS=6 };

// C = op(A)*B with optional fused epilogue. Tiles 64x64x16, block 256 (16x16),
// 4x4 microtile/thread. All dims are multiples of tile sizes (1024/16384).
template<int EPI, bool TA>
__global__ __launch_bounds__(256)
void gemm_k(const float* __restrict__ A, const float* __restrict__ B,
            float* __restrict__ C,
            const float* __restrict__ E1, const float* __restrict__ E2,
            const float* __restrict__ scal, const float* __restrict__ bias,
            int M, int N, int K, int lda,
            long zA, long zB, long zC, long zE,
            float ca, float cb, float cc)
{
  const int z = blockIdx.z;
  A += (long)z * zA;
  B += (long)z * zB;
  C += (long)z * zC;
  if (EPI==EPI_POLY || EPI==EPI_Y0 || EPI==EPI_G) E1 += (long)z * zE;
  if (EPI==EPI_Y0 || EPI==EPI_G)                  E2 += (long)z * zE;

  __shared__ float As[16][68]; // [k][m], padded
  __shared__ float Bs[16][68]; // [k][n], padded

  const int tid = threadIdx.x;
  const int tx = tid & 15, ty = tid >> 4;
  const int row0 = blockIdx.y * 64, col0 = blockIdx.x * 64;

  float acc[4][4];
  #pragma unroll
  for (int i=0;i<4;++i)
    #pragma unroll
    for (int j=0;j<4;++j) acc[i][j] = 0.f;

  for (int k0 = 0; k0 < K; k0 += 16) {
    if (TA) { // A-op(m,k) = A[k][m], A is K x M (lda = M)
      const int kk = tid >> 4, mq = tid & 15;
      const float4 v = *(const float4*)(A + (size_t)(k0+kk)*lda + row0 + mq*4);
      *(float4*)(&As[kk][mq*4]) = v;
    } else {  // A is M x K (lda = K)
      const int m = tid >> 2, kq = tid & 3;
      const float4 v = *(const float4*)(A + (size_t)(row0+m)*lda + k0 + kq*4);
      As[kq*4+0][m] = v.x; As[kq*4+1][m] = v.y;
      As[kq*4+2][m] = v.z; As[kq*4+3][m] = v.w;
    }
    {
      const int kk = tid >> 4, nq = tid & 15;
      const float4 v = *(const float4*)(B + (size_t)(k0+kk)*N + col0 + nq*4);
      *(float4*)(&Bs[kk][nq*4]) = v;
    }
    __syncthreads();
    #pragma unroll
    for (int kk=0; kk<16; ++kk) {
      const float4 av = *(const float4*)(&As[kk][ty*4]);
      const float4 bv = *(const float4*)(&Bs[kk][tx*4]);
      const float a4[4] = {av.x, av.y, av.z, av.w};
      const float b4[4] = {bv.x, bv.y, bv.z, bv.w};
      #pragma unroll
      for (int i=0;i<4;++i)
        #pragma unroll
        for (int j=0;j<4;++j)
          acc[i][j] = fmaf(a4[i], b4[j], acc[i][j]);
    }
    __syncthreads();
  }

  float sc = 0.f;
  if (EPI==EPI_Y0 || EPI==EPI_G) sc = scal[z];

  #pragma unroll
  for (int i=0;i<4;++i) {
    const int r = row0 + ty*4 + i;
    #pragma unroll
    for (int j=0;j<4;++j) {
      const int c = col0 + tx*4 + j;
      const size_t o = (size_t)r * N + c;
      const float a = acc[i][j];
      const float d = (r==c) ? 1.f : 0.f;
      float v;
      if      (EPI==EPI_NONE) v = a;
      else if (EPI==EPI_POLY) v = ca*d + cb*E1[o] + cc*a;                 // T = aI + bX^2 + cX^4
      else if (EPI==EPI_Y0)   v = sc*(d + E1[o] + E2[o] - a);            // (I+Z+H-HZ)/(2 s2)
      else if (EPI==EPI_TC)   v = 1.5f*d - 0.5f*a;                       // (3I - Zc Y)/2
      else if (EPI==EPI_G)    v = 0.5f*d + 0.5f*E1[o] + sc*(E2[o] - a);  // (I+Z)/2 + g(Zc - Z Zc)
      else if (EPI==EPI_BACT) { const float u = a + bias[c]; v = u / (1.1f*(1.f + expf(-u))); }
      else                    { v = a + bias[c]; }
      C[o] = v;
    }
  }
}

__global__ void zero_k(float* __restrict__ scal) {
  if (threadIdx.x < 16) scal[threadIdx.x] = 0.f;
}

// sum of squares of a 1M-float buffer per z -> scal[z]
__global__ __launch_bounds__(256)
void reduce_k(const float* __restrict__ v, float* __restrict__ scal) {
  __shared__ float s[256];
  const int z = blockIdx.z;
  const size_t base = (size_t)z*MUL + (size_t)blockIdx.x*4096 + threadIdx.x;
  float t = 0.f;
  #pragma unroll
  for (int i=0;i<16;++i) { const float x = v[base + i*256]; t = fmaf(x, x, t); }
  s[threadIdx.x] = t; __syncthreads();
  for (int o=128;o>0;o>>=1) { if (threadIdx.x<o) s[threadIdx.x]+=s[threadIdx.x+o]; __syncthreads(); }
  if (threadIdx.x==0) atomicAdd(&scal[z], s[0]);
}

// derive per-layer normalization scalars from ||H^2||_F^2
__global__ void scal_k(float* __restrict__ scal) {
  const int z = threadIdx.x;
  if (z < 3) {
    const float sumsq = scal[z];
    const float frobH2 = sqrtf(sumsq);     // ||H^2||_F
    const float bnd = sqrtf(frobH2);       // lambda_max(H) <= sqrt(||H^2||_F)
    const float sn = 0.81f + bnd;          // sign-init divisor (strict bound on |c^2 I - H|)
    const float s2 = 0.5f * sn;            // M' normalizer
    scal[4 + z]  = 1.f / sn;               // sign init scale
    scal[8 + z]  = 1.f / (2.f * s2);       // Y0 scale: 1/(2 s2)
    scal[12 + z] = 0.45f / sqrtf(s2);      // gamma = c/(2 sqrt(s2))
  }
}

// X0 = (c^2 I - H) / sn
__global__ __launch_bounds__(256)
void signinit_k(const float* __restrict__ H, float* __restrict__ X,
                const float* __restrict__ scal) {
  const int z = blockIdx.z;
  const int g = blockIdx.x*256 + threadIdx.x;
  const int r = g >> 10, c = g & 1023;
  const size_t o = (size_t)z*MUL + g;
  X[o] = (((r==c) ? 0.81f : 0.f) - H[o]) * scal[4 + z];
}

__global__ __launch_bounds__(256)
void identinit_k(float* __restrict__ V) {
  const int z = blockIdx.z;
  const int g = blockIdx.x*256 + threadIdx.x;
  const int r = g >> 10, c = g & 1023;
  V[(size_t)z*MUL + g] = (r==c) ? 1.f : 0.f;
}

extern "C" void kernel_launch(void* const* d_in, const int* in_sizes, int n_in,
                              void* d_out, int out_size, void* d_ws, size_t ws_size,
                              hipStream_t stream) {
  const float* x = (const float*)d_in[0];
  const float* w[3] = {(const float*)d_in[1], (const float*)d_in[3], (const float*)d_in[5]};
  const float* b[3] = {(const float*)d_in[2], (const float*)d_in[4], (const float*)d_in[6]};
  float* out = (float*)d_out;
  float* ws  = (float*)d_ws;

  // ws layout (units of MUL floats):
  //  0..2  Wb        (persists to K-GEMM)
  //  3..5  H         (dead after Y0-init; reused as Y-pong)
  //  6..8  S2: sign ping -> Z
  //  9..11 S3: H2 / sign pong / Y0(Y ping) / G
  // 12..14 S4: sign T / Zc0 (Zc ping)
  // 15     pad
  // 16..18 S5: Zc pong (final Zc lands here)
  // 19..21 S6: Tc / K  (K persists into main phase)
  // 22M    scalars (16 floats)
  // Main phase: act1 = ws+0 (16M floats) aliases slots 0..4 (all dead by then).
  if (ws_size < (size_t)(22*MUL + 64) * sizeof(float)) return; // refuse to corrupt

  float* Wb = ws + 0*MUL;
  float* H  = ws + 3*MUL;
  float* S2 = ws + 6*MUL;
  float* S3 = ws + 9*MUL;
  float* S4 = ws + 12*MUL;
  float* S5 = ws + 16*MUL;
  float* S6 = ws + 19*MUL;
  float* scal = ws + 22*MUL;
  float* act1 = ws; // main phase only

  for (int z=0; z<3; ++z)
    hipMemcpyAsync(Wb + (long)z*MUL, w[z], MUL*sizeof(float),
                   hipMemcpyDeviceToDevice, stream);

  const dim3 blk(256);
  const dim3 gsq(16, 16, 3);

  zero_k<<<1, 64, 0, stream>>>(scal);

  // H = W^T W
  gemm_k<EPI_NONE, true><<<gsq, blk, 0, stream>>>(
      Wb, Wb, H, nullptr, nullptr, nullptr, nullptr,
      1024, 1024, 1024, 1024, MUL, MUL, MUL, 0, 0.f, 0.f, 0.f);
  // H2 = H*H -> S3 (for lambda_max bound)
  gemm_k<EPI_NONE, false><<<gsq, blk, 0, stream>>>(
      H, H, S3, nullptr, nullptr, nullptr, nullptr,
      1024, 1024, 1024, 1024, MUL, MUL, MUL, 0, 0.f, 0.f, 0.f);
  reduce_k<<<dim3(256,1,3), blk, 0, stream>>>(S3, scal);
  scal_k<<<1, 64, 0, stream>>>(scal);
  signinit_k<<<dim3(4096,1,3), blk, 0, stream>>>(H, S2, scal);

  // --- Z = sign(c^2 I - H): 6 quintic (Muon) + 4 cubic NS iterations ---
  {
    float* Xc = S2; float* Q = S3; float* T = S4;
    for (int it=0; it<10; ++it) {
      float a_, b_, c_;
      if (it < 6) { a_ = 3.4445f; b_ = -4.7750f; c_ = 2.0315f; }
      else        { a_ = 1.5f;    b_ = -0.5f;    c_ = 0.f;     }
      // Q = X*X
      gemm_k<EPI_NONE, false><<<gsq, blk, 0, stream>>>(
          Xc, Xc, Q, nullptr, nullptr, nullptr, nullptr,
          1024, 1024, 1024, 1024, MUL, MUL, MUL, 0, 0.f, 0.f, 0.f);
      // T = a I + b Q + c (Q*Q)
      gemm_k<EPI_POLY, false><<<gsq, blk, 0, stream>>>(
          Q, Q, T, Q, nullptr, nullptr, nullptr,
          1024, 1024, 1024, 1024, MUL, MUL, MUL, MUL, a_, b_, c_);
      // Xnew = X*T  (into Q slot; Q's contents dead)
      gemm_k<EPI_NONE, false><<<gsq, blk, 0, stream>>>(
          Xc, T, Q, nullptr, nullptr, nullptr, nullptr,
          1024, 1024, 1024, 1024, MUL, MUL, MUL, 0, 0.f, 0.f, 0.f);
      float* tmp = Xc; Xc = Q; Q = tmp;
    }
    // 10 iterations (even) -> Z ends in S2
  }
  float* Z = S2;

  // --- Y0 = (I + Z + H - H*Z)/(2 s2) -> S3 ; Zc0 = I -> S4 ---
  gemm_k<EPI_Y0, false><<<gsq, blk, 0, stream>>>(
      H, Z, S3, Z, H, scal + 8, nullptr,
      1024, 1024, 1024, 1024, MUL, MUL, MUL, MUL, 0.f, 0.f, 0.f);
  identinit_k<<<dim3(4096,1,3), blk, 0, stream>>>(S4);

  // --- coupled NS inverse-sqrt: Zc -> (M'/s2)^{-1/2} (7 iters; last skips Y) ---
  {
    float* Yc = S3; float* Yp = H;
    float* Vc = S4; float* Vp = S5;
    float* R  = S6;
    for (int it=0; it<7; ++it) {
      // R = (3I - Zc*Y)/2
      gemm_k<EPI_TC, false><<<gsq, blk, 0, stream>>>(
          Vc, Yc, R, nullptr, nullptr, nullptr, nullptr,
          1024, 1024, 1024, 1024, MUL, MUL, MUL, 0, 0.f, 0.f, 0.f);
      if (it < 6) {
        // Ynew = Y*R
        gemm_k<EPI_NONE, false><<<gsq, blk, 0, stream>>>(
            Yc, R, Yp, nullptr, nullptr, nullptr, nullptr,
            1024, 1024, 1024, 1024, MUL, MUL, MUL, 0, 0.f, 0.f, 0.f);
      }
      // Zcnew = R*Zc
      gemm_k<EPI_NONE, false><<<gsq, blk, 0, stream>>>(
          R, Vc, Vp, nullptr, nullptr, nullptr, nullptr,
          1024, 1024, 1024, 1024, MUL, MUL, MUL, 0, 0.f, 0.f, 0.f);
      float* t1 = Yc; Yc = Yp; Yp = t1;
      float* t2 = Vc; Vc = Vp; Vp = t2;
    }
    // 7 iterations (odd) -> Zc ends in S5
  }
  float* Zc = S5;

  // --- G = (I+Z)/2 + gamma*(Zc - Z*Zc) -> S3 ---
  gemm_k<EPI_G, false><<<gsq, blk, 0, stream>>>(
      Z, Zc, S3, Z, Zc, scal + 12, nullptr,
      1024, 1024, 1024, 1024, MUL, MUL, MUL, MUL, 0.f, 0.f, 0.f);
  // --- K = W*G -> S6 ---
  gemm_k<EPI_NONE, false><<<gsq, blk, 0, stream>>>(
      Wb, S3, S6, nullptr, nullptr, nullptr, nullptr,
      1024, 1024, 1024, 1024, MUL, MUL, MUL, 0, 0.f, 0.f, 0.f);
  float* K = S6;

  // --- main path: 16384x1024 GEMMs, bias+lipswish epilogues ---
  const dim3 gm(16, 256, 1);
  gemm_k<EPI_BACT, false><<<gm, blk, 0, stream>>>(
      x, K + 0*MUL, out, nullptr, nullptr, nullptr, b[0],
      16384, 1024, 1024, 1024, 0, 0, 0, 0, 0.f, 0.f, 0.f);
  gemm_k<EPI_BACT, false><<<gm, blk, 0, stream>>>(
      out, K + 1*MUL, act1, nullptr, nullptr, nullptr, b[1],
      16384, 1024, 1024, 1024, 0, 0, 0, 0, 0.f, 0.f, 0.f);
  gemm_k<EPI_BIAS, false><<<gm, blk, 0, stream>>>(
      act1, K + 2*MUL, out, nullptr, nullptr, nullptr, b[2],
      16384, 1024, 1024, 1024, 0, 0, 0, 0, 0.f, 0.f, 0.f);
}

// Round 5
// 2759.488 us; speedup vs baseline: 2.6656x; 2.6656x over previous
//
#include <hip/hip_runtime.h>
#include <hip/hip_bf16.h>
#include <math.h>

// ---------------------------------------------------------------------------
// InvertibleDenseBlockSVD via SVD-free spectral clip (algorithm == R1):
//   H = W^T W ; Z = sign(c^2 I - H) (6 quintic + 4 cubic NS)
//   M' = (H(I-Z)+I+Z)/2 ; Zc = (M'/s2)^{-1/2} (7 coupled-NS iters)
//   G = (I+Z)/2 + gamma (Zc - Z Zc) ; K = W G ; y = act(x K + b)
// R4/R5: split-f16 ("double-f16") MFMA engine for the chain. Every chain
// matrix is stored as hi+lo f16 planes (lo = exact residual); products use 3
// MFMAs (ah*bh + ah*bl + al*bh) -> ~2^-20 effective precision == fp32-quality
// chain (R1 floor 0.0039) at MFMA speed. Main path single-f16 A, split-Kt B.
// All GEMMs NT (C = A * Bt^T); chain matrices symmetric => no transposes.
// ---------------------------------------------------------------------------

typedef _Float16 f16;
typedef f16 half8 __attribute__((ext_vector_type(8)));
typedef float f32x4 __attribute__((ext_vector_type(4)));

static const int  MULH = 1 << 20;   // elements per 1024x1024 plane
static const long LOFF = 3l << 20;  // hi->lo plane offset (3 z-planes)

enum { EPI_NONE=0, EPI_POLY=1, EPI_XT=2, EPI_Y0=3, EPI_TC=4, EPI_G=5, EPI_BACT=6, EPI_BIAS=7 };

typedef const __attribute__((address_space(1))) unsigned int* gp_t;
typedef __attribute__((address_space(3))) unsigned int* lp_t;

__device__ __forceinline__ void gload16(const void* g, void* l) {
  // 16B/lane, dest = wave-uniform LDS base + lane*16 (HW rule)
  __builtin_amdgcn_global_load_lds((gp_t)g, (lp_t)l, 16, 0, 0);
}

__device__ __forceinline__ float spl(const f16* __restrict__ p, size_t o) {
  return (float)p[o] + (float)p[o + LOFF];
}

// Split NT GEMM: C = A * Bt^T (+ epilogue). A: MxK row-major, Bt: NxK.
// B always split (hi + lo at +LOFF); A split iff SPLITA. Tile 128x128x32,
// 4 waves, each wave 64x64 via 4x4 mfma_f32_16x16x32_f16.
// Chain EPIs write split pairs; BACT writes single f16; BIAS writes fp32.
template<int EPI, bool SPLITA>
__global__ __launch_bounds__(256)
void sgemm(const f16* __restrict__ A, const f16* __restrict__ Bt,
           void* __restrict__ Cv,
           const f16* __restrict__ E1, const f16* __restrict__ E2,
           const float* __restrict__ scal, const float* __restrict__ bias,
           int M, int N, int K,
           long zA, long zB, long zC, long zE,
           float ca, float cb, float cc)
{
  const int z = blockIdx.z;
  A  += (long)z * zA;
  Bt += (long)z * zB;
  const long eoff = (long)z * zE;
  const int row0 = blockIdx.y * 128, col0 = blockIdx.x * 128;

  __shared__ __align__(16) f16 sm[16384]; // Ah | Al | Bh | Bl, 8KB planes
  char* Ahs = (char*)sm;
  char* Als = (char*)(sm + 4096);
  char* Bhs = (char*)(sm + 8192);
  char* Bls = (char*)(sm + 12288);

  const int tid  = threadIdx.x;
  const int w    = tid >> 6, lane = tid & 63;
  const int wr   = w >> 1,  wc   = w & 1;
  const int g    = lane >> 4, r15 = lane & 15;

  // staging: per plane, 8 chunks of 1KB; wave w stages chunks 2w, 2w+1.
  // LDS linear; global source pre-swizzled: LDS (row, slot s) holds k-group
  // s ^ ((row>>1)&3)  (involution; both-sides rule)
  const int ci0 = (w*2 + 0)*64 + lane;
  const int ci1 = (w*2 + 1)*64 + lane;
  const int ra0 = ci0 >> 2, sa0 = ((ci0 & 3) ^ ((ra0 >> 1) & 3)) * 8;
  const int ra1 = ci1 >> 2, sa1 = ((ci1 & 3) ^ ((ra1 >> 1) & 3)) * 8;
  const f16* gA0 = A  + (size_t)(row0 + ra0)*K + sa0;
  const f16* gA1 = A  + (size_t)(row0 + ra1)*K + sa1;
  const f16* gB0 = Bt + (size_t)(col0 + ra0)*K + sa0;
  const f16* gB1 = Bt + (size_t)(col0 + ra1)*K + sa1;
  char* dAh0 = Ahs + (w*2+0)*1024; char* dAh1 = Ahs + (w*2+1)*1024;
  char* dAl0 = Als + (w*2+0)*1024; char* dAl1 = Als + (w*2+1)*1024;
  char* dBh0 = Bhs + (w*2+0)*1024; char* dBh1 = Bhs + (w*2+1)*1024;
  char* dBl0 = Bls + (w*2+0)*1024; char* dBl1 = Bls + (w*2+1)*1024;

  // fragment read offsets (same involution); m/n stride = 16 rows * 64B
  const int soff = (g ^ ((r15 >> 1) & 3)) * 16;
  const int offA = (wr*64 + r15)*64 + soff;
  const int offB = (wc*64 + r15)*64 + soff;

  f32x4 acc[4][4] = {};

  for (int k0 = 0; k0 < K; k0 += 32) {
    gload16(gA0, dAh0); gload16(gA1, dAh1);
    if (SPLITA) { gload16(gA0 + LOFF, dAl0); gload16(gA1 + LOFF, dAl1); }
    gload16(gB0, dBh0); gload16(gB1, dBh1);
    gload16(gB0 + LOFF, dBl0); gload16(gB1 + LOFF, dBl1);
    gA0 += 32; gA1 += 32; gB0 += 32; gB1 += 32;
    __syncthreads();  // drains vmcnt -> LDS tile ready
    half8 ah[4], al[4], bh[4], bl[4];
    #pragma unroll
    for (int m=0;m<4;++m) {
      ah[m] = *(const half8*)(Ahs + offA + m*1024);
      if (SPLITA) al[m] = *(const half8*)(Als + offA + m*1024);
    }
    #pragma unroll
    for (int n=0;n<4;++n) {
      bh[n] = *(const half8*)(Bhs + offB + n*1024);
      bl[n] = *(const half8*)(Bls + offB + n*1024);
    }
    #pragma unroll
    for (int m=0;m<4;++m)
      #pragma unroll
      for (int n=0;n<4;++n) {
        acc[m][n] = __builtin_amdgcn_mfma_f32_16x16x32_f16(ah[m], bh[n], acc[m][n], 0, 0, 0);
        acc[m][n] = __builtin_amdgcn_mfma_f32_16x16x32_f16(ah[m], bl[n], acc[m][n], 0, 0, 0);
        if (SPLITA)
          acc[m][n] = __builtin_amdgcn_mfma_f32_16x16x32_f16(al[m], bh[n], acc[m][n], 0, 0, 0);
      }
    __syncthreads();  // protect LDS before next stage
  }

  float sc = 0.f;
  if (EPI==EPI_Y0 || EPI==EPI_G) sc = scal[z];

  // C/D layout (m89-verified): col = lane&15, row = (lane>>4)*4 + reg
  #pragma unroll
  for (int m=0;m<4;++m) {
    #pragma unroll
    for (int n=0;n<4;++n) {
      #pragma unroll
      for (int q=0;q<4;++q) {
        const int r = row0 + wr*64 + m*16 + g*4 + q;
        const int c = col0 + wc*64 + n*16 + r15;
        const size_t o = (size_t)r * N + c;
        const float a = acc[m][n][q];
        const float d = (r==c) ? 1.f : 0.f;
        float v;
        if      (EPI==EPI_NONE) v = a;
        else if (EPI==EPI_POLY) v = ca*d + cb*spl(E1, eoff+o) + cc*a;          // T = aI + bQ + cQ^2
        else if (EPI==EPI_XT)   v = 1.5f*spl(E1, eoff+o) - 0.5f*a;             // 1.5X - 0.5 XQ
        else if (EPI==EPI_Y0)   v = sc*(d + spl(E1, eoff+o) + spl(E2, eoff+o) - a);
        else if (EPI==EPI_TC)   v = 1.5f*d - 0.5f*a;
        else if (EPI==EPI_G)    v = 0.5f*d + 0.5f*spl(E1, eoff+o) + sc*(spl(E2, eoff+o) - a);
        else if (EPI==EPI_BACT) { const float u = a + bias[c]; v = u / (1.1f*(1.f + __expf(-u))); }
        else                    { v = a + bias[c]; }
        if      (EPI==EPI_BIAS) ((float*)Cv)[(size_t)zC*z + o] = v;
        else if (EPI==EPI_BACT) ((f16*) Cv)[(size_t)zC*z + o] = (f16)v;
        else {
          f16* C = (f16*)Cv;
          const f16 h = (f16)v;
          C[(size_t)zC*z + o] = h;
          C[(size_t)zC*z + LOFF + o] = (f16)(v - (float)h);  // exact residual
        }
      }
    }
  }
}

__global__ void zero_k(float* __restrict__ scal) {
  if (threadIdx.x < 16) scal[threadIdx.x] = 0.f;
}

// sum of squares of a 1M-f16 hi-plane per z -> scal[z]
__global__ __launch_bounds__(256)
void reduce_k(const f16* __restrict__ v, float* __restrict__ scal) {
  __shared__ float s[256];
  const int z = blockIdx.z;
  const f16* p = v + (size_t)z*MULH + (size_t)blockIdx.x*4096 + threadIdx.x*8;
  float t = 0.f;
  half8 h0 = *(const half8*)(p);
  half8 h1 = *(const half8*)(p + 2048);
  #pragma unroll
  for (int j=0;j<8;++j) { float a=(float)h0[j], b=(float)h1[j]; t = fmaf(a,a,fmaf(b,b,t)); }
  s[threadIdx.x] = t; __syncthreads();
  for (int o=128;o>0;o>>=1) { if (threadIdx.x<o) s[threadIdx.x]+=s[threadIdx.x+o]; __syncthreads(); }
  if (threadIdx.x==0) atomicAdd(&scal[z], s[0]);
}

// derive per-layer normalization scalars from ||H^2||_F^2 (identical to R1)
__global__ void scal_k(float* __restrict__ scal) {
  const int z = threadIdx.x;
  if (z < 3) {
    const float sumsq = scal[z];
    const float frobH2 = sqrtf(sumsq);
    const float bnd = sqrtf(frobH2);       // lambda_max(H) <= sqrt(||H^2||_F)
    const float sn = 0.81f + bnd;
    const float s2 = 0.5f * sn;
    scal[4 + z]  = 1.f / sn;
    scal[8 + z]  = 1.f / (2.f * s2);
    scal[12 + z] = 0.45f / sqrtf(s2);      // gamma = c/(2 sqrt(s2))
  }
}

// X0 = (c^2 I - H)/sn, split in -> split out
__global__ __launch_bounds__(256)
void signinit_k(const f16* __restrict__ H, f16* __restrict__ X,
                const float* __restrict__ scal) {
  const int z = blockIdx.z;
  const int gI = blockIdx.x*256 + threadIdx.x;
  const int r = gI >> 10, c = gI & 1023;
  const size_t o = (size_t)z*MULH + gI;
  const float hv = (float)H[o] + (float)H[o + LOFF];
  const float v = (((r==c) ? 0.81f : 0.f) - hv) * scal[4 + z];
  const f16 h = (f16)v;
  X[o] = h; X[o + LOFF] = (f16)(v - (float)h);
}

__global__ __launch_bounds__(256)
void identinit_k(f16* __restrict__ V) {
  const int z = blockIdx.z;
  const int gI = blockIdx.x*256 + threadIdx.x;
  const int r = gI >> 10, c = gI & 1023;
  const size_t o = (size_t)z*MULH + gI;
  V[o] = (r==c) ? (f16)1.f : (f16)0.f;
  V[o + LOFF] = (f16)0.f;
}

// fp32 -> split f16 pair (straight), z selects among 3 weight matrices
__global__ __launch_bounds__(256)
void c32s_k(const float* __restrict__ w0, const float* __restrict__ w1,
            const float* __restrict__ w2, f16* __restrict__ hi) {
  const float* s = blockIdx.z==0 ? w0 : (blockIdx.z==1 ? w1 : w2);
  f16* h = hi + (size_t)blockIdx.z*MULH;
  const int i = (blockIdx.x*256 + threadIdx.x)*4;
  const float4 a = *(const float4*)(s + i);
  const float av[4] = {a.x, a.y, a.z, a.w};
  #pragma unroll
  for (int j=0;j<4;++j) {
    const f16 hh = (f16)av[j];
    h[i+j] = hh; h[LOFF + i+j] = (f16)(av[j] - (float)hh);
  }
}

// Wht[z][i][j] = split(W_z[j][i])
__global__ __launch_bounds__(256)
void t32s_k(const float* __restrict__ w0, const float* __restrict__ w1,
            const float* __restrict__ w2, f16* __restrict__ dst) {
  const float* W = blockIdx.z==0 ? w0 : (blockIdx.z==1 ? w1 : w2);
  f16* Dh = dst + (size_t)blockIdx.z*MULH;
  __shared__ float t[32][33];
  const int tx = threadIdx.x & 31, ty = threadIdx.x >> 5;
  const int bx = blockIdx.x*32, by = blockIdx.y*32;
  #pragma unroll
  for (int p=0;p<4;++p)
    t[ty + p*8][tx] = W[(size_t)(by + ty + p*8)*1024 + bx + tx];
  __syncthreads();
  #pragma unroll
  for (int p=0;p<4;++p) {
    const float v = t[tx][ty + p*8];
    const f16 h = (f16)v;
    const size_t o = (size_t)(bx + ty + p*8)*1024 + by + tx;
    Dh[o] = h; Dh[o + LOFF] = (f16)(v - (float)h);
  }
}

// fp32 -> single f16 (for x)
__global__ __launch_bounds__(256)
void c32to16_k(const float* __restrict__ src, f16* __restrict__ dst, long n) {
  const long i = ((long)blockIdx.x*256 + threadIdx.x)*8;
  if (i >= n) return;
  const float4 a = *(const float4*)(src + i);
  const float4 b = *(const float4*)(src + i + 4);
  half8 h;
  h[0]=(f16)a.x; h[1]=(f16)a.y; h[2]=(f16)a.z; h[3]=(f16)a.w;
  h[4]=(f16)b.x; h[5]=(f16)b.y; h[6]=(f16)b.z; h[7]=(f16)b.w;
  *(half8*)(dst + i) = h;
}

extern "C" void kernel_launch(void* const* d_in, const int* in_sizes, int n_in,
                              void* d_out, int out_size, void* d_ws, size_t ws_size,
                              hipStream_t stream) {
  const float* x  = (const float*)d_in[0];
  const float* w0 = (const float*)d_in[1]; const float* b0 = (const float*)d_in[2];
  const float* w1 = (const float*)d_in[3]; const float* b1 = (const float*)d_in[4];
  const float* w2 = (const float*)d_in[5]; const float* b2 = (const float*)d_in[6];
  float* out = (float*)d_out;

  // ws: 42 MULH f16 (84MB) + scalars. Split slots (6 planes: hi z0-2, lo z0-2):
  //   Wh[0..6) Wht[6..12) H[12..18) D[18..24) E[24..30) F[30..36) G[36..42)
  // Chain: sign in D/E/F -> Z=F; NS over G/C(H)/B(Wht)/D/E -> Zc=D; Gm->C;
  // Kt(split) -> G-slot. Main (after Kt): xh[0..16) single, y1[16..32), y2=xh.
  if (ws_size < (size_t)42*MULH*2 + 64) return; // refuse to corrupt
  f16* hb = (f16*)d_ws;
  auto mat = [&](int i){ return hb + (size_t)i*MULH; };
  f16 *Wh = mat(0), *Wht = mat(6), *H = mat(12);
  f16 *D = mat(18), *E = mat(24), *F = mat(30), *G = mat(36);
  f16 *xh = mat(0), *y1 = mat(16), *y2 = mat(0);
  float* scal = (float*)((char*)d_ws + (size_t)42*MULH*2);

  const dim3 blk(256);
  const dim3 gsq(8, 8, 3);
  const dim3 gm(8, 128, 1);
  const long MU = MULH;

  t32s_k<<<dim3(32,32,3), blk, 0, stream>>>(w0, w1, w2, Wht);
  c32s_k<<<dim3(1024,1,3), blk, 0, stream>>>(w0, w1, w2, Wh);
  zero_k<<<1, 64, 0, stream>>>(scal);

  // H = W^T W = NT(Wht, Wht)
  sgemm<EPI_NONE,true><<<gsq, blk, 0, stream>>>(Wht, Wht, H, nullptr, nullptr, nullptr, nullptr,
      1024,1024,1024, MU,MU,MU,0, 0,0,0);
  // H2 -> D (for lambda_max bound)
  sgemm<EPI_NONE,true><<<gsq, blk, 0, stream>>>(H, H, D, nullptr, nullptr, nullptr, nullptr,
      1024,1024,1024, MU,MU,MU,0, 0,0,0);
  reduce_k<<<dim3(256,1,3), blk, 0, stream>>>(D, scal);
  scal_k<<<1, 64, 0, stream>>>(scal);
  signinit_k<<<dim3(4096,1,3), blk, 0, stream>>>(H, D, scal);  // X -> D

  // --- Z = sign(c^2 I - H): 6 quintic + 4 cubic ---
  f16 *X = D, *F1 = E, *F2 = F;
  for (int it=0; it<6; ++it) {
    sgemm<EPI_NONE,true><<<gsq, blk, 0, stream>>>(X, X, F1, nullptr, nullptr, nullptr, nullptr,
        1024,1024,1024, MU,MU,MU,0, 0,0,0);                               // Q = X^2
    sgemm<EPI_POLY,true><<<gsq, blk, 0, stream>>>(F1, F1, F2, F1, nullptr, nullptr, nullptr,
        1024,1024,1024, MU,MU,MU,MU, 3.4445f, -4.7750f, 2.0315f);         // T
    sgemm<EPI_NONE,true><<<gsq, blk, 0, stream>>>(X, F2, F1, nullptr, nullptr, nullptr, nullptr,
        1024,1024,1024, MU,MU,MU,0, 0,0,0);                               // Xn = X T
    f16* t = X; X = F1; F1 = t;
  }
  for (int it=0; it<4; ++it) {
    sgemm<EPI_NONE,true><<<gsq, blk, 0, stream>>>(X, X, F1, nullptr, nullptr, nullptr, nullptr,
        1024,1024,1024, MU,MU,MU,0, 0,0,0);                               // Q = X^2
    sgemm<EPI_XT,true><<<gsq, blk, 0, stream>>>(X, F1, F2, X, nullptr, nullptr, nullptr,
        1024,1024,1024, MU,MU,MU,MU, 0,0,0);                              // Xn = 1.5X - 0.5 XQ
    f16* t = X; X = F2; F2 = F1; F1 = t;
  }
  f16* Z = X;  // = F by rotation trace

  // --- Y0 = (I + Z + H - H Z)/(2 s2) -> G ; Zc0 = I -> Wht slot ---
  sgemm<EPI_Y0,true><<<gsq, blk, 0, stream>>>(H, Z, G, Z, H, scal + 8, nullptr,
      1024,1024,1024, MU,MU,MU,MU, 0,0,0);
  identinit_k<<<dim3(4096,1,3), blk, 0, stream>>>(Wht);

  // --- coupled NS inverse sqrt (7 iters; last skips Y) ---
  {
    f16 *Yc = G, *Yp = H, *Vc = Wht, *Vp = D, *R = E;
    for (int it=0; it<7; ++it) {
      sgemm<EPI_TC,true><<<gsq, blk, 0, stream>>>(Vc, Yc, R, nullptr, nullptr, nullptr, nullptr,
          1024,1024,1024, MU,MU,MU,0, 0,0,0);                             // R = (3I - Zc Y)/2
      if (it < 6) {
        sgemm<EPI_NONE,true><<<gsq, blk, 0, stream>>>(Yc, R, Yp, nullptr, nullptr, nullptr, nullptr,
            1024,1024,1024, MU,MU,MU,0, 0,0,0);                           // Y' = Y R
        f16* t = Yc; Yc = Yp; Yp = t;
      }
      sgemm<EPI_NONE,true><<<gsq, blk, 0, stream>>>(R, Vc, Vp, nullptr, nullptr, nullptr, nullptr,
          1024,1024,1024, MU,MU,MU,0, 0,0,0);                             // Zc' = R Zc
      f16* t = Vc; Vc = Vp; Vp = t;
    }
    f16* Zc = Vc;  // = D by trace
    // G-matrix -> C(H slot, dead); then Kt = G W^T -> G slot (split)
    sgemm<EPI_G,true><<<gsq, blk, 0, stream>>>(Z, Zc, H, Z, Zc, scal + 12, nullptr,
        1024,1024,1024, MU,MU,MU,MU, 0,0,0);
    sgemm<EPI_NONE,true><<<gsq, blk, 0, stream>>>(H, Wh, G, nullptr, nullptr, nullptr, nullptr,
        1024,1024,1024, MU,MU,MU,0, 0,0,0);                               // Kt(split)
  }

  // --- main path (after Kt; xh/y1/y2 alias dead chain slots) ---
  c32to16_k<<<8192, blk, 0, stream>>>(x, xh, (long)16384*1024);
  sgemm<EPI_BACT,false><<<gm, blk, 0, stream>>>(xh, G + 0*MU, y1, nullptr, nullptr, nullptr, b0,
      16384,1024,1024, 0,0,0,0, 0,0,0);
  sgemm<EPI_BACT,false><<<gm, blk, 0, stream>>>(y1, G + 1*MU, y2, nullptr, nullptr, nullptr, b1,
      16384,1024,1024, 0,0,0,0, 0,0,0);
  sgemm<EPI_BIAS,false><<<gm, blk, 0, stream>>>(y2, G + 2*MU, out, nullptr, nullptr, nullptr, b2,
      16384,1024,1024, 0,0,0,0, 0,0,0);
}

// Round 7
// 2004.509 us; speedup vs baseline: 3.6695x; 1.3766x over previous
//
#include <hip/hip_runtime.h>
#include <hip/hip_bf16.h>
#include <math.h>

// ---------------------------------------------------------------------------
// InvertibleDenseBlockSVD via SVD-free spectral clip (algorithm == R1):
//   H = W^T W ; Z = sign(c^2 I - H) (6 quintic + 4 cubic NS)
//   M' = (H(I-Z)+I+Z)/2 ; Zc = (M'/s2)^{-1/2} (6 coupled-NS iters)
//   G = (I+Z)/2 + gamma (Zc - Z Zc) ; K = W G ; y = act(x K + b)
// R6/R7: same split-f16 math as R5 (absmax 0.0039 = fp32 floor). Engine:
//   - double-buffered LDS, ONE barrier per k-step (prefetch drain hidden
//     under MFMA instead of serial vmcnt(0) stall)
//   - 64x64 tiles for square chain GEMMs -> 768 blocks (3/CU TLP) vs 192
//   - bijective XCD swizzle (gridDim.x==16, n%8==0) for L2 locality
//   - coupled-NS 7 -> 6 iters (residual 4e-7 << split noise)
// ---------------------------------------------------------------------------

typedef _Float16 f16;
typedef f16 half8 __attribute__((ext_vector_type(8)));
typedef float f32x4 __attribute__((ext_vector_type(4)));

static const int  MULH = 1 << 20;   // elements per 1024x1024 plane
static const long LOFF = 3l << 20;  // hi->lo plane offset (3 z-planes)

enum { EPI_NONE=0, EPI_POLY=1, EPI_XT=2, EPI_Y0=3, EPI_TC=4, EPI_G=5, EPI_BACT=6, EPI_BIAS=7 };

typedef const __attribute__((address_space(1))) unsigned int* gp_t;
typedef __attribute__((address_space(3))) unsigned int* lp_t;

__device__ __forceinline__ void gload16(const void* g, void* l) {
  // 16B/lane, dest = wave-uniform LDS base + lane*16 (HW rule)
  __builtin_amdgcn_global_load_lds((gp_t)g, (lp_t)l, 16, 0, 0);
}

__device__ __forceinline__ float spl(const f16* __restrict__ p, size_t o) {
  return (float)p[o] + (float)p[o + LOFF];
}

// Split NT GEMM: C = A * Bt^T (+ epilogue). A: MxK row-major, Bt: NxK.
// B always split (hi + lo at +LOFF); A split iff SPLITA. Tile BMxBNx32,
// 4 waves (2x2), wave = (BM/2)x(BN/2) via (BM/32)x(BN/32) 16x16x32 frags.
// Double-buffered LDS: stage(t+1) -> compute(t) -> ONE __syncthreads (its
// implicit vmcnt(0) drains the prefetch, hidden under compute).
template<int EPI, bool SPLITA, int BM, int BN>
__global__ __launch_bounds__(256)
void sgemm(const f16* __restrict__ A, const f16* __restrict__ Bt,
           void* __restrict__ Cv,
           const f16* __restrict__ E1, const f16* __restrict__ E2,
           const float* __restrict__ scal, const float* __restrict__ bias,
           int M, int N, int K,
           long zA, long zB, long zC, long zE,
           float ca, float cb, float cc)
{
  // XCD-aware bijective swizzle: id -> (id%8)*(n/8) + id/8. Both launch
  // grids have gridDim.x == 16 and n % 8 == 0. L2 locality only.
  int bx, by;
  {
    const int id = blockIdx.x + (blockIdx.y << 4);
    const int cpx = gridDim.y << 1;           // n/8 = 16*gy/8
    const int sw = (id & 7)*cpx + (id >> 3);
    bx = sw & 15; by = sw >> 4;
  }
  const int z = blockIdx.z;
  A  += (long)z * zA;
  Bt += (long)z * zB;
  const long eoff = (long)z * zE;
  const int row0 = by * BM, col0 = bx * BN;

  constexpr int ASZB = BM*64;                  // bytes per A plane (32k * 2B)
  constexpr int BSZB = BN*64;
  constexpr int OAL  = ASZB;                   // Al offset (SPLITA only)
  constexpr int OBH  = SPLITA ? 2*ASZB : ASZB;
  constexpr int OBL  = OBH + BSZB;
  constexpr int BUFS = OBL + BSZB;             // one buffer
  constexpr int NAW  = BM/64;                  // staging chunks per wave (A)
  constexpr int NBW  = BN/64;
  constexpr int MF   = BM/32;                  // frags per wave
  constexpr int NF   = BN/32;

  __shared__ __align__(16) char sm[2*BUFS];

  const int tid  = threadIdx.x;
  const int w    = tid >> 6, lane = tid & 63;
  const int wr   = w >> 1,  wc   = w & 1;
  const int g    = lane >> 4, r15 = lane & 15;

  // --- staging pointers. Slot s = chunk*64 + lane covers row = s>>2,
  // 16B-slot sl = s&3; source pre-swizzled so LDS (row, sl) holds k-group
  // sl ^ ((row>>1)&3) (involution; matches fragment-read swizzle).
  const f16 *gA[NAW], *gB[NBW];
  int cA[NAW], cB[NBW];
  #pragma unroll
  for (int i=0;i<NAW;++i) {
    const int c = w + i*4, s = c*64 + lane;
    const int row = s >> 2, sl = s & 3;
    cA[i] = c;
    gA[i] = A + (size_t)(row0 + row)*K + (sl ^ ((row>>1)&3))*8;
  }
  #pragma unroll
  for (int i=0;i<NBW;++i) {
    const int c = w + i*4, s = c*64 + lane;
    const int row = s >> 2, sl = s & 3;
    cB[i] = c;
    gB[i] = Bt + (size_t)(col0 + row)*K + (sl ^ ((row>>1)&3))*8;
  }

  auto stage = [&](int b) {
    char* base = sm + b*BUFS;
    #pragma unroll
    for (int i=0;i<NAW;++i) {
      gload16(gA[i], base + cA[i]*1024);
      if (SPLITA) gload16(gA[i] + LOFF, base + OAL + cA[i]*1024);
      gA[i] += 32;
    }
    #pragma unroll
    for (int i=0;i<NBW;++i) {
      gload16(gB[i],        base + OBH + cB[i]*1024);
      gload16(gB[i] + LOFF, base + OBL + cB[i]*1024);
      gB[i] += 32;
    }
  };

  // fragment read offsets (same involution); row stride 64B, frag = 16 rows
  const int soff = (g ^ ((r15 >> 1) & 3)) * 16;
  const int offA = (wr*(BM/2) + r15)*64 + soff;
  const int offB = (wc*(BN/2) + r15)*64 + soff;

  f32x4 acc[MF][NF] = {};

  stage(0);
  __syncthreads();
  int p = 0;
  for (int k0 = 0; k0 < K; k0 += 32) {
    if (k0 + 32 < K) stage(p ^ 1);       // prefetch next tile (other buffer)
    char* base = sm + p*BUFS;
    half8 ah[MF], al[MF], bh[NF], bl[NF];
    #pragma unroll
    for (int m=0;m<MF;++m) {
      ah[m] = *(const half8*)(base + offA + m*1024);
      if (SPLITA) al[m] = *(const half8*)(base + OAL + offA + m*1024);
    }
    #pragma unroll
    for (int n=0;n<NF;++n) {
      bh[n] = *(const half8*)(base + OBH + offB + n*1024);
      bl[n] = *(const half8*)(base + OBL + offB + n*1024);
    }
    #pragma unroll
    for (int m=0;m<MF;++m)
      #pragma unroll
      for (int n=0;n<NF;++n) {
        acc[m][n] = __builtin_amdgcn_mfma_f32_16x16x32_f16(ah[m], bh[n], acc[m][n], 0, 0, 0);
        acc[m][n] = __builtin_amdgcn_mfma_f32_16x16x32_f16(ah[m], bl[n], acc[m][n], 0, 0, 0);
        if (SPLITA)
          acc[m][n] = __builtin_amdgcn_mfma_f32_16x16x32_f16(al[m], bh[n], acc[m][n], 0, 0, 0);
      }
    __syncthreads();  // implicit vmcnt(0): prefetch landed; LDS reuse safe
    p ^= 1;
  }

  float sc = 0.f;
  if (EPI==EPI_Y0 || EPI==EPI_G) sc = scal[z];

  // C/D layout (m89-verified): col = lane&15, row = (lane>>4)*4 + reg
  #pragma unroll
  for (int m=0;m<MF;++m) {
    #pragma unroll
    for (int n=0;n<NF;++n) {
      #pragma unroll
      for (int q=0;q<4;++q) {
        const int r = row0 + wr*(BM/2) + m*16 + g*4 + q;
        const int c = col0 + wc*(BN/2) + n*16 + r15;
        const size_t o = (size_t)r * N + c;
        const float a = acc[m][n][q];
        const float d = (r==c) ? 1.f : 0.f;
        float v;
        if      (EPI==EPI_NONE) v = a;
        else if (EPI==EPI_POLY) v = ca*d + cb*spl(E1, eoff+o) + cc*a;          // T = aI + bQ + cQ^2
        else if (EPI==EPI_XT)   v = 1.5f*spl(E1, eoff+o) - 0.5f*a;             // 1.5X - 0.5 XQ
        else if (EPI==EPI_Y0)   v = sc*(d + spl(E1, eoff+o) + spl(E2, eoff+o) - a);
        else if (EPI==EPI_TC)   v = 1.5f*d - 0.5f*a;
        else if (EPI==EPI_G)    v = 0.5f*d + 0.5f*spl(E1, eoff+o) + sc*(spl(E2, eoff+o) - a);
        else if (EPI==EPI_BACT) { const float u = a + bias[c]; v = u / (1.1f*(1.f + __expf(-u))); }
        else                    { v = a + bias[c]; }
        if      (EPI==EPI_BIAS) ((float*)Cv)[(size_t)zC*z + o] = v;
        else if (EPI==EPI_BACT) ((f16*) Cv)[(size_t)zC*z + o] = (f16)v;
        else {
          f16* C = (f16*)Cv;
          const f16 h = (f16)v;
          C[(size_t)zC*z + o] = h;
          C[(size_t)zC*z + LOFF + o] = (f16)(v - (float)h);  // exact residual
        }
      }
    }
  }
}

__global__ void zero_k(float* __restrict__ scal) {
  if (threadIdx.x < 16) scal[threadIdx.x] = 0.f;
}

// sum of squares of a 1M-f16 hi-plane per z -> scal[z]
__global__ __launch_bounds__(256)
void reduce_k(const f16* __restrict__ v, float* __restrict__ scal) {
  __shared__ float s[256];
  const int z = blockIdx.z;
  const f16* p = v + (size_t)z*MULH + (size_t)blockIdx.x*4096 + threadIdx.x*8;
  float t = 0.f;
  half8 h0 = *(const half8*)(p);
  half8 h1 = *(const half8*)(p + 2048);
  #pragma unroll
  for (int j=0;j<8;++j) { float a=(float)h0[j], b=(float)h1[j]; t = fmaf(a,a,fmaf(b,b,t)); }
  s[threadIdx.x] = t; __syncthreads();
  for (int o=128;o>0;o>>=1) { if (threadIdx.x<o) s[threadIdx.x]+=s[threadIdx.x+o]; __syncthreads(); }
  if (threadIdx.x==0) atomicAdd(&scal[z], s[0]);
}

// derive per-layer normalization scalars from ||H^2||_F^2
__global__ void scal_k(float* __restrict__ scal) {
  const int z = threadIdx.x;
  if (z < 3) {
    const float sumsq = scal[z];
    const float frobH2 = sqrtf(sumsq);
    const float bnd = sqrtf(frobH2);       // lambda_max(H) <= sqrt(||H^2||_F)
    const float sn = 0.81f + bnd;
    const float s2 = 0.5f * sn;
    scal[4 + z]  = 1.f / sn;
    scal[8 + z]  = 1.f / (2.f * s2);
    scal[12 + z] = 0.45f / sqrtf(s2);      // gamma = c/(2 sqrt(s2))
  }
}

// X0 = (c^2 I - H)/sn, split in -> split out
__global__ __launch_bounds__(256)
void signinit_k(const f16* __restrict__ H, f16* __restrict__ X,
                const float* __restrict__ scal) {
  const int z = blockIdx.z;
  const int gI = blockIdx.x*256 + threadIdx.x;
  const int r = gI >> 10, c = gI & 1023;
  const size_t o = (size_t)z*MULH + gI;
  const float hv = (float)H[o] + (float)H[o + LOFF];
  const float v = (((r==c) ? 0.81f : 0.f) - hv) * scal[4 + z];
  const f16 h = (f16)v;
  X[o] = h; X[o + LOFF] = (f16)(v - (float)h);
}

__global__ __launch_bounds__(256)
void identinit_k(f16* __restrict__ V) {
  const int z = blockIdx.z;
  const int gI = blockIdx.x*256 + threadIdx.x;
  const int r = gI >> 10, c = gI & 1023;
  const size_t o = (size_t)z*MULH + gI;
  V[o] = (r==c) ? (f16)1.f : (f16)0.f;
  V[o + LOFF] = (f16)0.f;
}

// fp32 -> split f16 pair (straight), z selects among 3 weight matrices
__global__ __launch_bounds__(256)
void c32s_k(const float* __restrict__ w0, const float* __restrict__ w1,
            const float* __restrict__ w2, f16* __restrict__ hi) {
  const float* s = blockIdx.z==0 ? w0 : (blockIdx.z==1 ? w1 : w2);
  f16* h = hi + (size_t)blockIdx.z*MULH;
  const int i = (blockIdx.x*256 + threadIdx.x)*4;
  const float4 a = *(const float4*)(s + i);
  const float av[4] = {a.x, a.y, a.z, a.w};
  #pragma unroll
  for (int j=0;j<4;++j) {
    const f16 hh = (f16)av[j];
    h[i+j] = hh; h[LOFF + i+j] = (f16)(av[j] - (float)hh);
  }
}

// Wht[z][i][j] = split(W_z[j][i])
__global__ __launch_bounds__(256)
void t32s_k(const float* __restrict__ w0, const float* __restrict__ w1,
            const float* __restrict__ w2, f16* __restrict__ dst) {
  const float* W = blockIdx.z==0 ? w0 : (blockIdx.z==1 ? w1 : w2);
  f16* Dh = dst + (size_t)blockIdx.z*MULH;
  __shared__ float t[32][33];
  const int tx = threadIdx.x & 31, ty = threadIdx.x >> 5;
  const int bx = blockIdx.x*32, by = blockIdx.y*32;
  #pragma unroll
  for (int p=0;p<4;++p)
    t[ty + p*8][tx] = W[(size_t)(by + ty + p*8)*1024 + bx + tx];
  __syncthreads();
  #pragma unroll
  for (int p=0;p<4;++p) {
    const float v = t[tx][ty + p*8];
    const f16 h = (f16)v;
    const size_t o = (size_t)(bx + ty + p*8)*1024 + by + tx;
    Dh[o] = h; Dh[o + LOFF] = (f16)(v - (float)h);
  }
}

// fp32 -> single f16 (for x)
__global__ __launch_bounds__(256)
void c32to16_k(const float* __restrict__ src, f16* __restrict__ dst, long n) {
  const long i = ((long)blockIdx.x*256 + threadIdx.x)*8;
  if (i >= n) return;
  const float4 a = *(const float4*)(src + i);
  const float4 b = *(const float4*)(src + i + 4);
  half8 h;
  h[0]=(f16)a.x; h[1]=(f16)a.y; h[2]=(f16)a.z; h[3]=(f16)a.w;
  h[4]=(f16)b.x; h[5]=(f16)b.y; h[6]=(f16)b.z; h[7]=(f16)b.w;
  *(half8*)(dst + i) = h;
}

extern "C" void kernel_launch(void* const* d_in, const int* in_sizes, int n_in,
                              void* d_out, int out_size, void* d_ws, size_t ws_size,
                              hipStream_t stream) {
  const float* x  = (const float*)d_in[0];
  const float* w0 = (const float*)d_in[1]; const float* b0 = (const float*)d_in[2];
  const float* w1 = (const float*)d_in[3]; const float* b1 = (const float*)d_in[4];
  const float* w2 = (const float*)d_in[5]; const float* b2 = (const float*)d_in[6];
  float* out = (float*)d_out;

  // ws: 42 MULH f16 (84MB) + scalars. Split slots (6 planes: hi z0-2, lo z0-2):
  //   Wh[0..6) Wht[6..12) H[12..18) D[18..24) E[24..30) F[30..36) G[36..42)
  // Chain: sign in D/E/F -> Z=F; NS(6) over G/H/Wht/D/E -> Zc=Wht; Gm->H;
  // Kt(split) -> G slot. Main (after Kt): xh[0..16) single, y1[16..32), y2=xh.
  if (ws_size < (size_t)42*MULH*2 + 64) return; // refuse to corrupt
  f16* hb = (f16*)d_ws;
  auto mat = [&](int i){ return hb + (size_t)i*MULH; };
  f16 *Wh = mat(0), *Wht = mat(6), *H = mat(12);
  f16 *D = mat(18), *E = mat(24), *F = mat(30), *G = mat(36);
  f16 *xh = mat(0), *y1 = mat(16), *y2 = mat(0);
  float* scal = (float*)((char*)d_ws + (size_t)42*MULH*2);

  const dim3 blk(256);
  const dim3 gsq(16, 16, 3);    // 64x64 tiles, 768 blocks
  const dim3 gm(16, 128, 1);    // 128x64 tiles, 2048 blocks
  const long MU = MULH;

  t32s_k<<<dim3(32,32,3), blk, 0, stream>>>(w0, w1, w2, Wht);
  c32s_k<<<dim3(1024,1,3), blk, 0, stream>>>(w0, w1, w2, Wh);
  zero_k<<<1, 64, 0, stream>>>(scal);

  #define SQ(epi, Aa, Bb, Cc, e1, e2, sc, a_, b_, c_) \
    sgemm<epi, true, 64, 64><<<gsq, blk, 0, stream>>>( \
        Aa, Bb, Cc, e1, e2, sc, nullptr, 1024,1024,1024, MU,MU,MU,MU, a_, b_, c_)

  // H = W^T W = NT(Wht, Wht)
  SQ(EPI_NONE, Wht, Wht, H, nullptr, nullptr, nullptr, 0,0,0);
  // H2 -> D (for lambda_max bound)
  SQ(EPI_NONE, H, H, D, nullptr, nullptr, nullptr, 0,0,0);
  reduce_k<<<dim3(256,1,3), blk, 0, stream>>>(D, scal);
  scal_k<<<1, 64, 0, stream>>>(scal);
  signinit_k<<<dim3(4096,1,3), blk, 0, stream>>>(H, D, scal);  // X -> D

  // --- Z = sign(c^2 I - H): 6 quintic + 4 cubic ---
  f16 *X = D, *F1 = E, *F2 = F;
  for (int it=0; it<6; ++it) {
    SQ(EPI_NONE, X, X, F1, nullptr, nullptr, nullptr, 0,0,0);              // Q = X^2
    SQ(EPI_POLY, F1, F1, F2, F1, nullptr, nullptr, 3.4445f, -4.7750f, 2.0315f); // T
    SQ(EPI_NONE, X, F2, F1, nullptr, nullptr, nullptr, 0,0,0);             // Xn = X T
    f16* t = X; X = F1; F1 = t;
  }
  for (int it=0; it<4; ++it) {
    SQ(EPI_NONE, X, X, F1, nullptr, nullptr, nullptr, 0,0,0);              // Q = X^2
    SQ(EPI_XT, X, F1, F2, X, nullptr, nullptr, 0,0,0);                     // Xn = 1.5X - 0.5 XQ
    f16* t = X; X = F2; F2 = F1; F1 = t;
  }
  f16* Z = X;  // = F by rotation trace

  // --- Y0 = (I + Z + H - H Z)/(2 s2) -> G ; Zc0 = I -> Wht slot ---
  SQ(EPI_Y0, H, Z, G, Z, H, scal + 8, 0,0,0);
  identinit_k<<<dim3(4096,1,3), blk, 0, stream>>>(Wht);

  // --- coupled NS inverse sqrt (6 iters; last skips Y) ---
  {
    f16 *Yc = G, *Yp = H, *Vc = Wht, *Vp = D, *R = E;
    for (int it=0; it<6; ++it) {
      SQ(EPI_TC, Vc, Yc, R, nullptr, nullptr, nullptr, 0,0,0);             // R = (3I - Zc Y)/2
      if (it < 5) {
        SQ(EPI_NONE, Yc, R, Yp, nullptr, nullptr, nullptr, 0,0,0);         // Y' = Y R
        f16* t = Yc; Yc = Yp; Yp = t;
      }
      SQ(EPI_NONE, R, Vc, Vp, nullptr, nullptr, nullptr, 0,0,0);           // Zc' = R Zc
      f16* t = Vc; Vc = Vp; Vp = t;
    }
    f16* Zc = Vc;  // = Wht by trace
    // G-matrix -> H slot (dead); then Kt = Gm W^T -> G slot (split)
    SQ(EPI_G, Z, Zc, H, Z, Zc, scal + 12, 0,0,0);
    SQ(EPI_NONE, H, Wh, G, nullptr, nullptr, nullptr, 0,0,0);              // Kt(split)
  }
  #undef SQ

  // --- main path (after Kt; xh/y1/y2 alias dead chain slots) ---
  c32to16_k<<<8192, blk, 0, stream>>>(x, xh, (long)16384*1024);
  sgemm<EPI_BACT, false, 128, 64><<<gm, blk, 0, stream>>>(
      xh, G + 0*MU, y1, nullptr, nullptr, nullptr, b0,
      16384,1024,1024, 0,0,0,0, 0,0,0);
  sgemm<EPI_BACT, false, 128, 64><<<gm, blk, 0, stream>>>(
      y1, G + 1*MU, y2, nullptr, nullptr, nullptr, b1,
      16384,1024,1024, 0,0,0,0, 0,0,0);
  sgemm<EPI_BIAS, false, 128, 64><<<gm, blk, 0, stream>>>(
      y2, G + 2*MU, out, nullptr, nullptr, nullptr, b2,
      16384,1024,1024, 0,0,0,0, 0,0,0);
}

// Round 8
// 1897.113 us; speedup vs baseline: 3.8772x; 1.0566x over previous
//
#include <hip/hip_runtime.h>
#include <hip/hip_bf16.h>
#include <math.h>

// ---------------------------------------------------------------------------
// InvertibleDenseBlockSVD via SVD-free spectral clip (algorithm == R1):
//   H = W^T W ; Z = sign(c^2 I - H) (6 quintic + 4 cubic NS)
//   M' = (H(I-Z)+I+Z)/2 ; Zc = (M'/s2)^{-1/2} (6 coupled-NS iters)
//   G = (I+Z)/2 + gamma (Zc - Z Zc) ; K = W G ; y = act(x K + b)
// R8: same split-f16 math as R5/R7 (absmax 0.0039 = fp32 floor). Engine:
//   - 3-deep global_load_lds pipeline, COUNTED vmcnt (never drains to 0 in
//     the main loop) + raw s_barrier pair per k-step (T3/T4). R7's single
//     __syncthreads implicitly drained vmcnt(0) each k-step -> serial
//     memory latency (~2475 cyc/k-step measured vs ~300 useful).
//   - triple-buffered LDS (48 KB), 64x64 square tiles (768 blocks),
//     128x64 main tiles, bijective XCD swizzle.
// ---------------------------------------------------------------------------

typedef _Float16 f16;
typedef f16 half8 __attribute__((ext_vector_type(8)));
typedef float f32x4 __attribute__((ext_vector_type(4)));

static const int  MULH = 1 << 20;   // elements per 1024x1024 plane
static const long LOFF = 3l << 20;  // hi->lo plane offset (3 z-planes)

enum { EPI_NONE=0, EPI_POLY=1, EPI_XT=2, EPI_Y0=3, EPI_TC=4, EPI_G=5, EPI_BACT=6, EPI_BIAS=7 };

typedef const __attribute__((address_space(1))) unsigned int* gp_t;
typedef __attribute__((address_space(3))) unsigned int* lp_t;

__device__ __forceinline__ void gload16(const void* g, void* l) {
  // 16B/lane, dest = wave-uniform LDS base + lane*16 (HW rule)
  __builtin_amdgcn_global_load_lds((gp_t)g, (lp_t)l, 16, 0, 0);
}

template<int N>
__device__ __forceinline__ void waitv() {
  asm volatile("s_waitcnt vmcnt(%0)" :: "n"(N) : "memory");
}

__device__ __forceinline__ float spl(const f16* __restrict__ p, size_t o) {
  return (float)p[o] + (float)p[o + LOFF];
}

// Split NT GEMM: C = A * Bt^T (+ epilogue). A: MxK row-major, Bt: NxK.
// B always split (hi + lo at +LOFF); A split iff SPLITA. Tile BMxBNx32,
// 4 waves (2x2), wave = (BM/2)x(BN/2) via (BM/32)x(BN/32) 16x16x32 frags.
// 3-deep pipeline: stage(t+2) issued at top of iter t; counted vmcnt(2*VST)
// guarantees stage(t) landed while t+1,t+2 stay in flight; raw barriers.
template<int EPI, bool SPLITA, int BM, int BN>
__global__ __launch_bounds__(256)
void sgemm(const f16* __restrict__ A, const f16* __restrict__ Bt,
           void* __restrict__ Cv,
           const f16* __restrict__ E1, const f16* __restrict__ E2,
           const float* __restrict__ scal, const float* __restrict__ bias,
           int M, int N, int K,
           long zA, long zB, long zC, long zE,
           float ca, float cb, float cc)
{
  // XCD-aware bijective swizzle: id -> (id%8)*(n/8) + id/8. Both launch
  // grids have gridDim.x == 16 and n % 8 == 0. L2 locality only.
  int bx, by;
  {
    const int id = blockIdx.x + (blockIdx.y << 4);
    const int cpx = gridDim.y << 1;           // n/8 = 16*gy/8
    const int sw = (id & 7)*cpx + (id >> 3);
    bx = sw & 15; by = sw >> 4;
  }
  const int z = blockIdx.z;
  A  += (long)z * zA;
  Bt += (long)z * zB;
  const long eoff = (long)z * zE;
  const int row0 = by * BM, col0 = bx * BN;

  constexpr int ASZB = BM*64;                  // bytes per A plane (rows*64B)
  constexpr int BSZB = BN*64;
  constexpr int OAL  = ASZB;                   // Al offset (SPLITA only)
  constexpr int OBH  = SPLITA ? 2*ASZB : ASZB;
  constexpr int OBL  = OBH + BSZB;
  constexpr int BUFS = OBL + BSZB;             // one buffer
  constexpr int NAW  = BM/64;                  // staging chunks per wave (A)
  constexpr int NBW  = BN/64;
  constexpr int MF   = BM/32;                  // frags per wave
  constexpr int NF   = BN/32;
  constexpr int VST  = NAW*(SPLITA?2:1) + NBW*2;  // vmem insts per stage/wave

  __shared__ __align__(16) char sm[3*BUFS];

  const int tid  = threadIdx.x;
  const int w    = tid >> 6, lane = tid & 63;
  const int wr   = w >> 1,  wc   = w & 1;
  const int g    = lane >> 4, r15 = lane & 15;

  // --- staging pointers. Slot s = chunk*64 + lane covers row = s>>2,
  // 16B-slot sl = s&3; source pre-swizzled so LDS (row, sl) holds k-group
  // sl ^ ((row>>1)&3) (involution; matches fragment-read swizzle).
  const f16 *gA[NAW], *gB[NBW];
  int cA[NAW], cB[NBW];
  #pragma unroll
  for (int i=0;i<NAW;++i) {
    const int c = w + i*4, s = c*64 + lane;
    const int row = s >> 2, sl = s & 3;
    cA[i] = c;
    gA[i] = A + (size_t)(row0 + row)*K + (sl ^ ((row>>1)&3))*8;
  }
  #pragma unroll
  for (int i=0;i<NBW;++i) {
    const int c = w + i*4, s = c*64 + lane;
    const int row = s >> 2, sl = s & 3;
    cB[i] = c;
    gB[i] = Bt + (size_t)(col0 + row)*K + (sl ^ ((row>>1)&3))*8;
  }

  auto stage = [&](int s) {
    char* base = sm + (s % 3)*BUFS;
    #pragma unroll
    for (int i=0;i<NAW;++i) {
      gload16(gA[i], base + cA[i]*1024);
      if (SPLITA) gload16(gA[i] + LOFF, base + OAL + cA[i]*1024);
      gA[i] += 32;
    }
    #pragma unroll
    for (int i=0;i<NBW;++i) {
      gload16(gB[i],        base + OBH + cB[i]*1024);
      gload16(gB[i] + LOFF, base + OBL + cB[i]*1024);
      gB[i] += 32;
    }
  };

  // fragment read offsets (same involution); row stride 64B, frag = 16 rows
  const int soff = (g ^ ((r15 >> 1) & 3)) * 16;
  const int offA = (wr*(BM/2) + r15)*64 + soff;
  const int offB = (wc*(BN/2) + r15)*64 + soff;

  f32x4 acc[MF][NF] = {};

  const int nk = K >> 5;
  stage(0); stage(1);
  for (int t = 0; t < nk; ++t) {
    // prefetch 2 ahead, then wait for stage(t) only (t+1, t+2 in flight)
    if (t + 2 < nk) { stage(t + 2); waitv<2*VST>(); }
    else if (t + 1 < nk) waitv<VST>();
    else waitv<0>();
    __builtin_amdgcn_s_barrier();       // stage(t) visible to all waves
    char* base = sm + (t % 3)*BUFS;
    half8 ah[MF], al[MF], bh[NF], bl[NF];
    #pragma unroll
    for (int m=0;m<MF;++m) {
      ah[m] = *(const half8*)(base + offA + m*1024);
      if (SPLITA) al[m] = *(const half8*)(base + OAL + offA + m*1024);
    }
    #pragma unroll
    for (int n=0;n<NF;++n) {
      bh[n] = *(const half8*)(base + OBH + offB + n*1024);
      bl[n] = *(const half8*)(base + OBL + offB + n*1024);
    }
    #pragma unroll
    for (int m=0;m<MF;++m)
      #pragma unroll
      for (int n=0;n<NF;++n) {
        acc[m][n] = __builtin_amdgcn_mfma_f32_16x16x32_f16(ah[m], bh[n], acc[m][n], 0, 0, 0);
        acc[m][n] = __builtin_amdgcn_mfma_f32_16x16x32_f16(ah[m], bl[n], acc[m][n], 0, 0, 0);
        if (SPLITA)
          acc[m][n] = __builtin_amdgcn_mfma_f32_16x16x32_f16(al[m], bh[n], acc[m][n], 0, 0, 0);
      }
    __builtin_amdgcn_s_barrier();       // all waves done reading buf t%3
  }

  float sc = 0.f;
  if (EPI==EPI_Y0 || EPI==EPI_G) sc = scal[z];

  // C/D layout (m89-verified): col = lane&15, row = (lane>>4)*4 + reg
  #pragma unroll
  for (int m=0;m<MF;++m) {
    #pragma unroll
    for (int n=0;n<NF;++n) {
      #pragma unroll
      for (int q=0;q<4;++q) {
        const int r = row0 + wr*(BM/2) + m*16 + g*4 + q;
        const int c = col0 + wc*(BN/2) + n*16 + r15;
        const size_t o = (size_t)r * N + c;
        const float a = acc[m][n][q];
        const float d = (r==c) ? 1.f : 0.f;
        float v;
        if      (EPI==EPI_NONE) v = a;
        else if (EPI==EPI_POLY) v = ca*d + cb*spl(E1, eoff+o) + cc*a;          // T = aI + bQ + cQ^2
        else if (EPI==EPI_XT)   v = 1.5f*spl(E1, eoff+o) - 0.5f*a;             // 1.5X - 0.5 XQ
        else if (EPI==EPI_Y0)   v = sc*(d + spl(E1, eoff+o) + spl(E2, eoff+o) - a);
        else if (EPI==EPI_TC)   v = 1.5f*d - 0.5f*a;
        else if (EPI==EPI_G)    v = 0.5f*d + 0.5f*spl(E1, eoff+o) + sc*(spl(E2, eoff+o) - a);
        else if (EPI==EPI_BACT) { const float u = a + bias[c]; v = u / (1.1f*(1.f + __expf(-u))); }
        else                    { v = a + bias[c]; }
        if      (EPI==EPI_BIAS) ((float*)Cv)[(size_t)zC*z + o] = v;
        else if (EPI==EPI_BACT) ((f16*) Cv)[(size_t)zC*z + o] = (f16)v;
        else {
          f16* C = (f16*)Cv;
          const f16 h = (f16)v;
          C[(size_t)zC*z + o] = h;
          C[(size_t)zC*z + LOFF + o] = (f16)(v - (float)h);  // exact residual
        }
      }
    }
  }
}

__global__ void zero_k(float* __restrict__ scal) {
  if (threadIdx.x < 16) scal[threadIdx.x] = 0.f;
}

// sum of squares of a 1M-f16 hi-plane per z -> scal[z]
__global__ __launch_bounds__(256)
void reduce_k(const f16* __restrict__ v, float* __restrict__ scal) {
  __shared__ float s[256];
  const int z = blockIdx.z;
  const f16* p = v + (size_t)z*MULH + (size_t)blockIdx.x*4096 + threadIdx.x*8;
  float t = 0.f;
  half8 h0 = *(const half8*)(p);
  half8 h1 = *(const half8*)(p + 2048);
  #pragma unroll
  for (int j=0;j<8;++j) { float a=(float)h0[j], b=(float)h1[j]; t = fmaf(a,a,fmaf(b,b,t)); }
  s[threadIdx.x] = t; __syncthreads();
  for (int o=128;o>0;o>>=1) { if (threadIdx.x<o) s[threadIdx.x]+=s[threadIdx.x+o]; __syncthreads(); }
  if (threadIdx.x==0) atomicAdd(&scal[z], s[0]);
}

// derive per-layer normalization scalars from ||H^2||_F^2
__global__ void scal_k(float* __restrict__ scal) {
  const int z = threadIdx.x;
  if (z < 3) {
    const float sumsq = scal[z];
    const float frobH2 = sqrtf(sumsq);
    const float bnd = sqrtf(frobH2);       // lambda_max(H) <= sqrt(||H^2||_F)
    const float sn = 0.81f + bnd;
    const float s2 = 0.5f * sn;
    scal[4 + z]  = 1.f / sn;
    scal[8 + z]  = 1.f / (2.f * s2);
    scal[12 + z] = 0.45f / sqrtf(s2);      // gamma = c/(2 sqrt(s2))
  }
}

// X0 = (c^2 I - H)/sn, split in -> split out
__global__ __launch_bounds__(256)
void signinit_k(const f16* __restrict__ H, f16* __restrict__ X,
                const float* __restrict__ scal) {
  const int z = blockIdx.z;
  const int gI = blockIdx.x*256 + threadIdx.x;
  const int r = gI >> 10, c = gI & 1023;
  const size_t o = (size_t)z*MULH + gI;
  const float hv = (float)H[o] + (float)H[o + LOFF];
  const float v = (((r==c) ? 0.81f : 0.f) - hv) * scal[4 + z];
  const f16 h = (f16)v;
  X[o] = h; X[o + LOFF] = (f16)(v - (float)h);
}

__global__ __launch_bounds__(256)
void identinit_k(f16* __restrict__ V) {
  const int z = blockIdx.z;
  const int gI = blockIdx.x*256 + threadIdx.x;
  const int r = gI >> 10, c = gI & 1023;
  const size_t o = (size_t)z*MULH + gI;
  V[o] = (r==c) ? (f16)1.f : (f16)0.f;
  V[o + LOFF] = (f16)0.f;
}

// fp32 -> split f16 pair (straight), z selects among 3 weight matrices
__global__ __launch_bounds__(256)
void c32s_k(const float* __restrict__ w0, const float* __restrict__ w1,
            const float* __restrict__ w2, f16* __restrict__ hi) {
  const float* s = blockIdx.z==0 ? w0 : (blockIdx.z==1 ? w1 : w2);
  f16* h = hi + (size_t)blockIdx.z*MULH;
  const int i = (blockIdx.x*256 + threadIdx.x)*4;
  const float4 a = *(const float4*)(s + i);
  const float av[4] = {a.x, a.y, a.z, a.w};
  #pragma unroll
  for (int j=0;j<4;++j) {
    const f16 hh = (f16)av[j];
    h[i+j] = hh; h[LOFF + i+j] = (f16)(av[j] - (float)hh);
  }
}

// Wht[z][i][j] = split(W_z[j][i])
__global__ __launch_bounds__(256)
void t32s_k(const float* __restrict__ w0, const float* __restrict__ w1,
            const float* __restrict__ w2, f16* __restrict__ dst) {
  const float* W = blockIdx.z==0 ? w0 : (blockIdx.z==1 ? w1 : w2);
  f16* Dh = dst + (size_t)blockIdx.z*MULH;
  __shared__ float t[32][33];
  const int tx = threadIdx.x & 31, ty = threadIdx.x >> 5;
  const int bx = blockIdx.x*32, by = blockIdx.y*32;
  #pragma unroll
  for (int p=0;p<4;++p)
    t[ty + p*8][tx] = W[(size_t)(by + ty + p*8)*1024 + bx + tx];
  __syncthreads();
  #pragma unroll
  for (int p=0;p<4;++p) {
    const float v = t[tx][ty + p*8];
    const f16 h = (f16)v;
    const size_t o = (size_t)(bx + ty + p*8)*1024 + by + tx;
    Dh[o] = h; Dh[o + LOFF] = (f16)(v - (float)h);
  }
}

// fp32 -> single f16 (for x)
__global__ __launch_bounds__(256)
void c32to16_k(const float* __restrict__ src, f16* __restrict__ dst, long n) {
  const long i = ((long)blockIdx.x*256 + threadIdx.x)*8;
  if (i >= n) return;
  const float4 a = *(const float4*)(src + i);
  const float4 b = *(const float4*)(src + i + 4);
  half8 h;
  h[0]=(f16)a.x; h[1]=(f16)a.y; h[2]=(f16)a.z; h[3]=(f16)a.w;
  h[4]=(f16)b.x; h[5]=(f16)b.y; h[6]=(f16)b.z; h[7]=(f16)b.w;
  *(half8*)(dst + i) = h;
}

extern "C" void kernel_launch(void* const* d_in, const int* in_sizes, int n_in,
                              void* d_out, int out_size, void* d_ws, size_t ws_size,
                              hipStream_t stream) {
  const float* x  = (const float*)d_in[0];
  const float* w0 = (const float*)d_in[1]; const float* b0 = (const float*)d_in[2];
  const float* w1 = (const float*)d_in[3]; const float* b1 = (const float*)d_in[4];
  const float* w2 = (const float*)d_in[5]; const float* b2 = (const float*)d_in[6];
  float* out = (float*)d_out;

  // ws: 42 MULH f16 (84MB) + scalars. Split slots (6 planes: hi z0-2, lo z0-2):
  //   Wh[0..6) Wht[6..12) H[12..18) D[18..24) E[24..30) F[30..36) G[36..42)
  // Chain: sign in D/E/F -> Z=F; NS(6) over G/H/Wht/D/E -> Zc=Wht; Gm->H;
  // Kt(split) -> G slot. Main (after Kt): xh[0..16) single, y1[16..32), y2=xh.
  if (ws_size < (size_t)42*MULH*2 + 64) return; // refuse to corrupt
  f16* hb = (f16*)d_ws;
  auto mat = [&](int i){ return hb + (size_t)i*MULH; };
  f16 *Wh = mat(0), *Wht = mat(6), *H = mat(12);
  f16 *D = mat(18), *E = mat(24), *F = mat(30), *G = mat(36);
  f16 *xh = mat(0), *y1 = mat(16), *y2 = mat(0);
  float* scal = (float*)((char*)d_ws + (size_t)42*MULH*2);

  const dim3 blk(256);
  const dim3 gsq(16, 16, 3);    // 64x64 tiles, 768 blocks
  const dim3 gm(16, 128, 1);    // 128x64 tiles, 2048 blocks
  const long MU = MULH;

  t32s_k<<<dim3(32,32,3), blk, 0, stream>>>(w0, w1, w2, Wht);
  c32s_k<<<dim3(1024,1,3), blk, 0, stream>>>(w0, w1, w2, Wh);
  zero_k<<<1, 64, 0, stream>>>(scal);

  #define SQ(epi, Aa, Bb, Cc, e1, e2, sc, a_, b_, c_) \
    sgemm<epi, true, 64, 64><<<gsq, blk, 0, stream>>>( \
        Aa, Bb, Cc, e1, e2, sc, nullptr, 1024,1024,1024, MU,MU,MU,MU, a_, b_, c_)

  // H = W^T W = NT(Wht, Wht)
  SQ(EPI_NONE, Wht, Wht, H, nullptr, nullptr, nullptr, 0,0,0);
  // H2 -> D (for lambda_max bound)
  SQ(EPI_NONE, H, H, D, nullptr, nullptr, nullptr, 0,0,0);
  reduce_k<<<dim3(256,1,3), blk, 0, stream>>>(D, scal);
  scal_k<<<1, 64, 0, stream>>>(scal);
  signinit_k<<<dim3(4096,1,3), blk, 0, stream>>>(H, D, scal);  // X -> D

  // --- Z = sign(c^2 I - H): 6 quintic + 4 cubic ---
  f16 *X = D, *F1 = E, *F2 = F;
  for (int it=0; it<6; ++it) {
    SQ(EPI_NONE, X, X, F1, nullptr, nullptr, nullptr, 0,0,0);              // Q = X^2
    SQ(EPI_POLY, F1, F1, F2, F1, nullptr, nullptr, 3.4445f, -4.7750f, 2.0315f); // T
    SQ(EPI_NONE, X, F2, F1, nullptr, nullptr, nullptr, 0,0,0);             // Xn = X T
    f16* t = X; X = F1; F1 = t;
  }
  for (int it=0; it<4; ++it) {
    SQ(EPI_NONE, X, X, F1, nullptr, nullptr, nullptr, 0,0,0);              // Q = X^2
    SQ(EPI_XT, X, F1, F2, X, nullptr, nullptr, 0,0,0);                     // Xn = 1.5X - 0.5 XQ
    f16* t = X; X = F2; F2 = F1; F1 = t;
  }
  f16* Z = X;  // = F by rotation trace

  // --- Y0 = (I + Z + H - H Z)/(2 s2) -> G ; Zc0 = I -> Wht slot ---
  SQ(EPI_Y0, H, Z, G, Z, H, scal + 8, 0,0,0);
  identinit_k<<<dim3(4096,1,3), blk, 0, stream>>>(Wht);

  // --- coupled NS inverse sqrt (6 iters; last skips Y) ---
  {
    f16 *Yc = G, *Yp = H, *Vc = Wht, *Vp = D, *R = E;
    for (int it=0; it<6; ++it) {
      SQ(EPI_TC, Vc, Yc, R, nullptr, nullptr, nullptr, 0,0,0);             // R = (3I - Zc Y)/2
      if (it < 5) {
        SQ(EPI_NONE, Yc, R, Yp, nullptr, nullptr, nullptr, 0,0,0);         // Y' = Y R
        f16* t = Yc; Yc = Yp; Yp = t;
      }
      SQ(EPI_NONE, R, Vc, Vp, nullptr, nullptr, nullptr, 0,0,0);           // Zc' = R Zc
      f16* t = Vc; Vc = Vp; Vp = t;
    }
    f16* Zc = Vc;  // = Wht by trace
    // G-matrix -> H slot (dead); then Kt = Gm W^T -> G slot (split)
    SQ(EPI_G, Z, Zc, H, Z, Zc, scal + 12, 0,0,0);
    SQ(EPI_NONE, H, Wh, G, nullptr, nullptr, nullptr, 0,0,0);              // Kt(split)
  }
  #undef SQ

  // --- main path (after Kt; xh/y1/y2 alias dead chain slots) ---
  c32to16_k<<<8192, blk, 0, stream>>>(x, xh, (long)16384*1024);
  sgemm<EPI_BACT, false, 128, 64><<<gm, blk, 0, stream>>>(
      xh, G + 0*MU, y1, nullptr, nullptr, nullptr, b0,
      16384,1024,1024, 0,0,0,0, 0,0,0);
  sgemm<EPI_BACT, false, 128, 64><<<gm, blk, 0, stream>>>(
      y1, G + 1*MU, y2, nullptr, nullptr, nullptr, b1,
      16384,1024,1024, 0,0,0,0, 0,0,0);
  sgemm<EPI_BIAS, false, 128, 64><<<gm, blk, 0, stream>>>(
      y2, G + 2*MU, out, nullptr, nullptr, nullptr, b2,
      16384,1024,1024, 0,0,0,0, 0,0,0);
}